// Round 2
// baseline (232.204 us; speedup 1.0000x reference)
//
#include <hip/hip_runtime.h>
#include <math.h>

// DeepseekV3 TopK router, MI355X — R11: persistent-block restructure.
// R10 post-mortem: phase-B LDS conflicts were already hidden (null delta) —
// the remaining kernel excess is the per-round synchronized HBM load stall
// (every block starts 16 waves/CU with 8 loads and zero compute cover, x8
// rounds). R11: 512 persistent blocks (2/CU), 4 token-slices each, with
// in-register chunked prefetch: slice i+1's loads issue mid-phase-A of slice
// i (into the x[] halves freed by chunks c=1/c=3), giving every load
// 1500-3000 cy of compute cover. Phase-B wave rotates per slice; single kbuf
// with a second barrier guarding overwrite. Bias staged in conflict-free
// padded LDS ([8][36]) to keep VGPR ~90 (no spill under bounds(512,4)).
// All score arithmetic frozen (expf, NR recip, u64 keys, Batcher networks)
// -> bit-identical outputs to R9/R10.

constexpr int N_EXPERTS  = 256;
constexpr int N_GROUP    = 8;
constexpr int EG         = 32;
constexpr int TOPK_GROUP = 4;
constexpr int TOP_K      = 8;
constexpr int BLOCK      = 512;              // 64 tokens per slice
constexpr int TPB_TOK    = BLOCK / N_GROUP;  // 64

typedef unsigned int u32;
typedef unsigned long long u64;

// monotone map: a<b (float) <=> M(a)<M(b) (u32)
__device__ __forceinline__ u32 fmono(float f) {
  const u32 u = __float_as_uint(f);
  return u ^ ((u32)((int)u >> 31) | 0x80000000u);
}
__device__ __forceinline__ float fmono_inv(u32 m) {
  const u32 u = (m & 0x80000000u) ? (m ^ 0x80000000u) : ~m;
  return __uint_as_float(u);
}
// key: larger = (bigger value, then smaller index)
__device__ __forceinline__ u64 mkkey(float v, int idx) {
  return ((u64)fmono(v) << 32) | (u32)(255 - idx);
}
__device__ __forceinline__ int key_idx(u64 k) { return 255 - (int)(k & 0xFFu); }
__device__ __forceinline__ float key_val(u64 k) { return fmono_inv((u32)(k >> 32)); }

// reciprocal of d in (1,2): v_rcp_f32 + 2 NR refinements. VCC-free, <=1 ulp.
__device__ __forceinline__ float recip_nr(float d) {
  float r = __builtin_amdgcn_rcpf(d);
  r = __builtin_fmaf(__builtin_fmaf(-d, r, 1.0f), r, r);
  r = __builtin_fmaf(__builtin_fmaf(-d, r, 1.0f), r, r);
  return r;
}

// descending compare-swap: larger key to a
__device__ __forceinline__ void kswap(u64& a, u64& b) {
  const bool sw = b > a;
  const u64 t = sw ? b : a;
  b = sw ? a : b;
  a = t;
}

// Batcher odd-even mergesort network for 8 (19 comparators), descending.
__device__ __forceinline__ void sort8(u64 (&k)[8]) {
  kswap(k[0], k[1]); kswap(k[2], k[3]); kswap(k[4], k[5]); kswap(k[6], k[7]);
  kswap(k[0], k[2]); kswap(k[1], k[3]); kswap(k[4], k[6]); kswap(k[5], k[7]);
  kswap(k[1], k[2]); kswap(k[5], k[6]);
  kswap(k[0], k[4]); kswap(k[1], k[5]); kswap(k[2], k[6]); kswap(k[3], k[7]);
  kswap(k[2], k[4]); kswap(k[3], k[5]);
  kswap(k[1], k[2]); kswap(k[3], k[4]); kswap(k[5], k[6]);
}

// A = top-8 of (A, B); both descending sorted. Keys are unique -> exact.
__device__ __forceinline__ void merge8(u64 (&A)[8], const u64 (&B)[8]) {
  u64 R[8];
#pragma unroll
  for (int i = 0; i < 8; ++i) {
    const bool a = A[i] >= B[7 - i];
    R[i] = a ? A[i] : B[7 - i];
  }
  kswap(R[0], R[4]); kswap(R[1], R[5]); kswap(R[2], R[6]); kswap(R[3], R[7]);
  kswap(R[0], R[2]); kswap(R[1], R[3]); kswap(R[4], R[6]); kswap(R[5], R[7]);
  kswap(R[0], R[1]); kswap(R[2], R[3]); kswap(R[4], R[5]); kswap(R[6], R[7]);
#pragma unroll
  for (int i = 0; i < 8; ++i) A[i] = R[i];
}

// phase-B list read: 4x ds_read_b128, conflict-free via the 2-level swizzle.
__device__ __forceinline__ void load_list(const ulonglong2 (*kb)[4], int j,
                                          int s, u64 (&L)[8]) {
  const int r  = 8 * j + s;
  const int rr = r ^ ((j >> 2) & 1);   // (r>>5)&1 == (j>>2)&1 since s<8
  const int sw = j & 3;                // (r>>3)&3 == j&3
  (void)r;
#pragma unroll
  for (int p = 0; p < 4; ++p) {
    const ulonglong2 v = kb[rr][p ^ sw];
    L[2 * p]     = v.x;
    L[2 * p + 1] = v.y;
  }
}

// one 8-element chunk: sigmoid+bias -> keys -> sort8 -> merge into K
__device__ __forceinline__ void chunk_sort(u64 (&K)[8], const float4 xa,
                                           const float4 xb, const float4 ba,
                                           const float4 bv, const int idx0,
                                           const bool first) {
  u64 C[8];
  const float xs[8] = {xa.x, xa.y, xa.z, xa.w, xb.x, xb.y, xb.z, xb.w};
  const float bs[8] = {ba.x, ba.y, ba.z, ba.w, bv.x, bv.y, bv.z, bv.w};
#pragma unroll
  for (int j = 0; j < 8; ++j) {
    const float e = expf(-xs[j]);                 // frozen: precise expf
    const float s = recip_nr(1.0f + e);           // 1/(1+e), VCC-free NR
    C[j] = mkkey(s + bs[j], idx0 + j);
  }
  sort8(C);
  if (first) {
#pragma unroll
    for (int j = 0; j < 8; ++j) K[j] = C[j];
  } else {
    merge8(K, C);
  }
}

// phase A on current x[] regs; prefetches next slice into freed x halves.
__device__ __forceinline__ void phase_a(u64 (&K)[8], float4 (&x)[8],
                                        const float4* brow, const float4*& rp,
                                        const int qbase, const bool pf) {
  chunk_sort(K, x[0], x[1], brow[0], brow[1], qbase + 0,  true);
  chunk_sort(K, x[2], x[3], brow[2], brow[3], qbase + 8,  false);
  if (pf) { x[0] = rp[0]; x[1] = rp[1]; x[2] = rp[2]; x[3] = rp[3]; }
  chunk_sort(K, x[4], x[5], brow[4], brow[5], qbase + 16, false);
  chunk_sort(K, x[6], x[7], brow[6], brow[7], qbase + 24, false);
  if (pf) {
    x[4] = rp[4]; x[5] = rp[5]; x[6] = rp[6]; x[7] = rp[7];
    rp += (TPB_TOK * N_EXPERTS) / 4;   // next slice (4096 float4s)
  }
}

// phase B: one lane per token — group top-4, merge 4 lists, epilogue.
__device__ __forceinline__ void phase_b(const float* gsb,
                                        const ulonglong2 (*kbuf)[4],
                                        const float (*bias_lds)[36],
                                        float* out, const int T,
                                        const int j, const int tok) {
  const float4* gp = reinterpret_cast<const float4*>(&gsb[8 * j]);
  const float4 ga = gp[0], gb = gp[1];
  const float g[N_GROUP] = {ga.x, ga.y, ga.z, ga.w, gb.x, gb.y, gb.z, gb.w};

  // top-4 groups (ties -> lower index), collected in ascending group order
  int s0 = 0, s1 = 0, s2 = 0, s3 = 0, cnt = 0;
#pragma unroll
  for (int h = 0; h < N_GROUP; ++h) {
    int rank = 0;
#pragma unroll
    for (int m = 0; m < N_GROUP; ++m)
      rank += (m < h) ? (g[m] >= g[h] ? 1 : 0) : (g[m] > g[h] ? 1 : 0);
    const bool pick = (rank < TOPK_GROUP);
    s0 = (pick && cnt == 0) ? h : s0;
    s1 = (pick && cnt == 1) ? h : s1;
    s2 = (pick && cnt == 2) ? h : s2;
    s3 = (pick && cnt == 3) ? h : s3;
    cnt += pick ? 1 : 0;
  }

  u64 A[8], Bv[8];
  load_list(kbuf, j, s0, A);
  load_list(kbuf, j, s1, Bv); merge8(A, Bv);
  load_list(kbuf, j, s2, Bv); merge8(A, Bv);
  load_list(kbuf, j, s3, Bv); merge8(A, Bv);

  float fi[8], sv[8];
  float sum = 0.0f;
#pragma unroll
  for (int k = 0; k < TOP_K; ++k) {
    const int idx = key_idx(A[k]);
    const float c = key_val(A[k]);
    sv[k] = c - bias_lds[idx >> 5][idx & 31];   // recover sigmoid score
    fi[k] = (float)idx;
    sum += sv[k];
  }
  const float scale = 2.5f / (sum + 1e-20f);

  float4* oi = reinterpret_cast<float4*>(out) + (size_t)tok * 2;
  oi[0] = make_float4(fi[0], fi[1], fi[2], fi[3]);
  oi[1] = make_float4(fi[4], fi[5], fi[6], fi[7]);
  float4* ow = reinterpret_cast<float4*>(out + (size_t)T * TOP_K) + (size_t)tok * 2;
  ow[0] = make_float4(sv[0] * scale, sv[1] * scale, sv[2] * scale, sv[3] * scale);
  ow[1] = make_float4(sv[4] * scale, sv[5] * scale, sv[6] * scale, sv[7] * scale);
}

__global__ __launch_bounds__(BLOCK, 4) void deepseek_topk_router_r11(
    const float* __restrict__ logits,
    const float* __restrict__ bias,
    float* __restrict__ out,   // [T*8] indices (as float) then [T*8] weights
    int T) {
  __shared__ __align__(16) float gsb[BLOCK];          // 2 KB group scores
  __shared__ ulonglong2 kbuf[BLOCK][4];               // 32 KB, swizzled
  __shared__ __align__(16) float bias_lds[N_GROUP][36];  // padded: rows on
                                                         // distinct bank grps

  const int tid = threadIdx.x;
  const int lq  = tid & 7;               // group handled by this lane
  const int lt  = tid >> 3;              // local token 0..63
  const int nIter  = (T / TPB_TOK) / gridDim.x;   // 4 at T=131072, grid=512
  const int slice0 = blockIdx.x * nIter;
  const int qbase  = lq * EG;

  if (tid < N_EXPERTS) bias_lds[tid >> 5][tid & 31] = bias[tid];

  // prologue: slice0 loads in flight before anything else
  const float4* rp = reinterpret_cast<const float4*>(
      logits + ((size_t)(slice0 * TPB_TOK + lt)) * N_EXPERTS + qbase);
  float4 x[8];
#pragma unroll
  for (int u = 0; u < 8; ++u) x[u] = rp[u];
  rp += (TPB_TOK * N_EXPERTS) / 4;

  __syncthreads();                       // bias_lds ready

  const float4* brow = reinterpret_cast<const float4*>(bias_lds[lq]);

  u64 K[8];
  phase_a(K, x, brow, rp, qbase, nIter > 1);   // slice0; prefetch slice1

  for (int i = 0; i < nIter; ++i) {
    // publish group score + sorted list for slice (slice0+i)
    gsb[tid] = key_val(K[0]) + key_val(K[1]);
    {
      const int rr = tid ^ ((tid >> 5) & 1);
      const int sw = (tid >> 3) & 3;
      kbuf[rr][0 ^ sw] = make_ulonglong2(K[0], K[1]);
      kbuf[rr][1 ^ sw] = make_ulonglong2(K[2], K[3]);
      kbuf[rr][2 ^ sw] = make_ulonglong2(K[4], K[5]);
      kbuf[rr][3 ^ sw] = make_ulonglong2(K[6], K[7]);
    }
    __syncthreads();                     // barrier A: publish visible

    // rotating phase-B wave; others overlap next slice's phase A.
    if ((tid >> 6) == (i & 7))
      phase_b(gsb, kbuf, bias_lds, out, T, tid & 63,
              (slice0 + i) * TPB_TOK + (tid & 63));

    if (i + 1 < nIter) {
      // registers/global/bias_lds only — no gsb/kbuf access before barrier B
      phase_a(K, x, brow, rp, qbase, i + 2 < nIter);
      __syncthreads();                   // barrier B: kbuf reads done,
                                         // safe to overwrite next iteration
    }
  }
}

extern "C" void kernel_launch(void* const* d_in, const int* in_sizes, int n_in,
                              void* d_out, int out_size, void* d_ws, size_t ws_size,
                              hipStream_t stream) {
  const float* logits = (const float*)d_in[0];
  const float* bias   = (const float*)d_in[1];
  float* out = (float*)d_out;
  const int T = in_sizes[0] / N_EXPERTS;       // 131072 (multiple of 64)
  const int nSlices = T / TPB_TOK;             // 2048
  int grid = 512;                              // 2 blocks/CU on 256 CUs
  if (nSlices % grid != 0) grid = nSlices;     // fallback: 1 slice/block
  deepseek_topk_router_r11<<<grid, BLOCK, 0, stream>>>(logits, bias, out, T);
}

// Round 6
// 202.418 us; speedup vs baseline: 1.1471x; 1.1471x over previous
//
#include <hip/hip_runtime.h>
#include <math.h>

// DeepseekV3 TopK router, MI355X — R12 (3rd resubmit; R3/R4/R5 benches were
// GPU-broker acquisition timeouts, no hardware data): de-spill + occupancy.
// R11 post-mortem: __launch_bounds__(512,4) was interpreted as min-BLOCKS/CU
// (CUDA semantics) -> 8 waves/EU -> 64-VGPR cap -> ~70MB of scratch spill
// traffic (WRITE_SIZE 78MB vs 8.4MB expected). R10 carried the same cap, so
// its LDS-swizzle null result was masked by spills. R12 reverts to the
// non-persistent R10 skeleton with: (1) no min-blocks bound; explicit
// amdgpu_waves_per_eu(6) -> ~80-VGPR cap, 3 blocks/CU (24 waves, 75% occ);
// (2) bias moved from a 32-reg bb[8] preload to a padded LDS table [8][36]
// (broadcast reads, rows on distinct bank groups) -> peak live ~72 regs, no
// spill; (3) full-row coalesced x[8] loads preserved. All score arithmetic
// frozen (precise expf, NR recip, u64 keys, Batcher networks) -> bit-identical.

constexpr int N_EXPERTS  = 256;
constexpr int N_GROUP    = 8;
constexpr int EG         = 32;
constexpr int TOPK_GROUP = 4;
constexpr int TOP_K      = 8;
constexpr int BLOCK      = 512;              // 64 tokens per block
constexpr int TPB_TOK    = BLOCK / N_GROUP;  // 64

typedef unsigned int u32;
typedef unsigned long long u64;

// monotone map: a<b (float) <=> M(a)<M(b) (u32)
__device__ __forceinline__ u32 fmono(float f) {
  const u32 u = __float_as_uint(f);
  return u ^ ((u32)((int)u >> 31) | 0x80000000u);
}
__device__ __forceinline__ float fmono_inv(u32 m) {
  const u32 u = (m & 0x80000000u) ? (m ^ 0x80000000u) : ~m;
  return __uint_as_float(u);
}
// key: larger = (bigger value, then smaller index)
__device__ __forceinline__ u64 mkkey(float v, int idx) {
  return ((u64)fmono(v) << 32) | (u32)(255 - idx);
}
__device__ __forceinline__ int key_idx(u64 k) { return 255 - (int)(k & 0xFFu); }
__device__ __forceinline__ float key_val(u64 k) { return fmono_inv((u32)(k >> 32)); }

// reciprocal of d in (1,2): v_rcp_f32 + 2 NR refinements. VCC-free, <=1 ulp.
__device__ __forceinline__ float recip_nr(float d) {
  float r = __builtin_amdgcn_rcpf(d);
  r = __builtin_fmaf(__builtin_fmaf(-d, r, 1.0f), r, r);
  r = __builtin_fmaf(__builtin_fmaf(-d, r, 1.0f), r, r);
  return r;
}

// descending compare-swap: larger key to a
__device__ __forceinline__ void kswap(u64& a, u64& b) {
  const bool sw = b > a;
  const u64 t = sw ? b : a;
  b = sw ? a : b;
  a = t;
}

// Batcher odd-even mergesort network for 8 (19 comparators), descending.
__device__ __forceinline__ void sort8(u64 (&k)[8]) {
  kswap(k[0], k[1]); kswap(k[2], k[3]); kswap(k[4], k[5]); kswap(k[6], k[7]);
  kswap(k[0], k[2]); kswap(k[1], k[3]); kswap(k[4], k[6]); kswap(k[5], k[7]);
  kswap(k[1], k[2]); kswap(k[5], k[6]);
  kswap(k[0], k[4]); kswap(k[1], k[5]); kswap(k[2], k[6]); kswap(k[3], k[7]);
  kswap(k[2], k[4]); kswap(k[3], k[5]);
  kswap(k[1], k[2]); kswap(k[3], k[4]); kswap(k[5], k[6]);
}

// A = top-8 of (A, B); both descending sorted. Keys are unique -> exact.
__device__ __forceinline__ void merge8(u64 (&A)[8], const u64 (&B)[8]) {
  u64 R[8];
#pragma unroll
  for (int i = 0; i < 8; ++i) {
    const bool a = A[i] >= B[7 - i];
    R[i] = a ? A[i] : B[7 - i];
  }
  kswap(R[0], R[4]); kswap(R[1], R[5]); kswap(R[2], R[6]); kswap(R[3], R[7]);
  kswap(R[0], R[2]); kswap(R[1], R[3]); kswap(R[4], R[6]); kswap(R[5], R[7]);
  kswap(R[0], R[1]); kswap(R[2], R[3]); kswap(R[4], R[5]); kswap(R[6], R[7]);
#pragma unroll
  for (int i = 0; i < 8; ++i) A[i] = R[i];
}

// phase-B list read: 4x ds_read_b128, conflict-free via the 2-level swizzle.
__device__ __forceinline__ void load_list(const ulonglong2 (*kb)[4], int j,
                                          int s, u64 (&L)[8]) {
  const int r  = 8 * j + s;
  const int rr = r ^ ((j >> 2) & 1);   // (r>>5)&1 == (j>>2)&1 since s<8
  const int sw = j & 3;                // (r>>3)&3 == j&3
  (void)r;
#pragma unroll
  for (int p = 0; p < 4; ++p) {
    const ulonglong2 v = kb[rr][p ^ sw];
    L[2 * p]     = v.x;
    L[2 * p + 1] = v.y;
  }
}

__global__ __launch_bounds__(BLOCK)
__attribute__((amdgpu_waves_per_eu(6)))
void deepseek_topk_router_r12(
    const float* __restrict__ logits,
    const float* __restrict__ bias,
    float* __restrict__ out,   // [T*8] indices (as float) then [T*8] weights
    int T) {
  __shared__ __align__(16) float gsb[BLOCK];             // 2 KB group scores
  __shared__ ulonglong2 kbuf[BLOCK][4];                  // 32 KB, swizzled
  __shared__ __align__(16) float bias_lds[N_GROUP][36];  // padded: row r on
                                                         // bank group 4r

  const int tid = threadIdx.x;
  const int id  = blockIdx.x * BLOCK + tid;
  const int t   = id >> 3;              // token (T*8 % 512 == 0, grid exact)
  const int q   = id & 7;               // group handled by this lane

  const float4* row4 =
      reinterpret_cast<const float4*>(logits + (size_t)t * N_EXPERTS + q * EG);

  // full 128B row per thread in flight before any dependent math
  float4 x[8];
#pragma unroll
  for (int u = 0; u < 8; ++u) x[u] = row4[u];

  // bias -> LDS (2-way write aliasing only = free), then barrier
  if (tid < N_EXPERTS) bias_lds[tid >> 5][tid & 31] = bias[tid];
  __syncthreads();
  const float4* brow = reinterpret_cast<const float4*>(bias_lds[q]);

  // ---- Phase A: sorted top-8 keys of my group's 32 corrected scores ----
  u64 K[8];
#pragma unroll
  for (int c = 0; c < 4; ++c) {
    u64 C[8];
    const float4 ba = brow[2 * c], bv = brow[2 * c + 1];   // LDS broadcast
    const float xs[8] = {x[2*c].x, x[2*c].y, x[2*c].z, x[2*c].w,
                         x[2*c+1].x, x[2*c+1].y, x[2*c+1].z, x[2*c+1].w};
    const float bs[8] = {ba.x, ba.y, ba.z, ba.w, bv.x, bv.y, bv.z, bv.w};
#pragma unroll
    for (int j = 0; j < 8; ++j) {
      const float e = expf(-xs[j]);                 // frozen: precise expf
      const float s = recip_nr(1.0f + e);           // 1/(1+e), VCC-free NR
      C[j] = mkkey(s + bs[j], q * EG + c * 8 + j);
    }
    sort8(C);
    if (c == 0) {
#pragma unroll
      for (int j = 0; j < 8; ++j) K[j] = C[j];
    } else {
      merge8(K, C);
    }
  }

  // ---- Publish group score + sorted list; single barrier ----
  gsb[tid] = key_val(K[0]) + key_val(K[1]);
  {
    const int rr = tid ^ ((tid >> 5) & 1);
    const int sw = (tid >> 3) & 3;
    kbuf[rr][0 ^ sw] = make_ulonglong2(K[0], K[1]);
    kbuf[rr][1 ^ sw] = make_ulonglong2(K[2], K[3]);
    kbuf[rr][2 ^ sw] = make_ulonglong2(K[4], K[5]);
    kbuf[rr][3 ^ sw] = make_ulonglong2(K[6], K[7]);
  }
  __syncthreads();
  if (tid >= TPB_TOK) return;           // waves 1..7 done

  // ---- Phase B: wave 0, one thread per token ----
  const int j   = tid;                  // local token
  const int tok = blockIdx.x * TPB_TOK + j;

  // 8 group scores (contiguous in gsb)
  const float4* gp = reinterpret_cast<const float4*>(&gsb[8 * j]);
  const float4 ga = gp[0], gb = gp[1];
  const float g[N_GROUP] = {ga.x, ga.y, ga.z, ga.w, gb.x, gb.y, gb.z, gb.w};

  // top-4 groups (ties -> lower index), collected in ascending group order
  int s0 = 0, s1 = 0, s2 = 0, s3 = 0, cnt = 0;
#pragma unroll
  for (int h = 0; h < N_GROUP; ++h) {
    int rank = 0;
#pragma unroll
    for (int m = 0; m < N_GROUP; ++m)
      rank += (m < h) ? (g[m] >= g[h] ? 1 : 0) : (g[m] > g[h] ? 1 : 0);
    const bool pick = (rank < TOPK_GROUP);
    s0 = (pick && cnt == 0) ? h : s0;
    s1 = (pick && cnt == 1) ? h : s1;
    s2 = (pick && cnt == 2) ? h : s2;
    s3 = (pick && cnt == 3) ? h : s3;
    cnt += pick ? 1 : 0;
  }

  // merge the 4 selected lists (key order is exact; any merge order OK)
  u64 A[8], Bv[8];
  load_list(kbuf, j, s0, A);
  load_list(kbuf, j, s1, Bv); merge8(A, Bv);
  load_list(kbuf, j, s2, Bv); merge8(A, Bv);
  load_list(kbuf, j, s3, Bv); merge8(A, Bv);

  // ---- Epilogue: weights = (c - bias[idx]) / sum * 2.5 ----
  float fi[8], sv[8];
  float sum = 0.0f;
#pragma unroll
  for (int k = 0; k < TOP_K; ++k) {
    const int idx = key_idx(A[k]);
    const float c = key_val(A[k]);
    sv[k] = c - bias[idx];              // recover sigmoid score (bias L1-hot)
    fi[k] = (float)idx;
    sum += sv[k];
  }
  const float scale = 2.5f / (sum + 1e-20f);  // once per token: IEEE is fine

  float4* oi = reinterpret_cast<float4*>(out) + (size_t)tok * 2;
  oi[0] = make_float4(fi[0], fi[1], fi[2], fi[3]);
  oi[1] = make_float4(fi[4], fi[5], fi[6], fi[7]);
  float4* ow = reinterpret_cast<float4*>(out + (size_t)T * TOP_K) + (size_t)tok * 2;
  ow[0] = make_float4(sv[0] * scale, sv[1] * scale, sv[2] * scale, sv[3] * scale);
  ow[1] = make_float4(sv[4] * scale, sv[5] * scale, sv[6] * scale, sv[7] * scale);
}

extern "C" void kernel_launch(void* const* d_in, const int* in_sizes, int n_in,
                              void* d_out, int out_size, void* d_ws, size_t ws_size,
                              hipStream_t stream) {
  const float* logits = (const float*)d_in[0];
  const float* bias   = (const float*)d_in[1];
  float* out = (float*)d_out;
  const int T = in_sizes[0] / N_EXPERTS;           // 131072 (multiple of 64)
  const int blocks = T / TPB_TOK;                   // 2048
  deepseek_topk_router_r12<<<blocks, BLOCK, 0, stream>>>(logits, bias, out, T);
}